// Round 1
// baseline (1492.877 us; speedup 1.0000x reference)
//
#include <hip/hip_runtime.h>

typedef float f32x4 __attribute__((ext_vector_type(4)));
typedef __bf16 bf16x8 __attribute__((ext_vector_type(8)));
typedef unsigned short ushort4v __attribute__((ext_vector_type(4)));

#define GLOBAL_AS __attribute__((address_space(1)))
#define LDS_AS    __attribute__((address_space(3)))

static __device__ __forceinline__ void gload16(const void* g, void* l) {
  __builtin_amdgcn_global_load_lds((const GLOBAL_AS void*)g, (LDS_AS void*)l, 16, 0, 0);
}

// ---------------- fp32 -> bf16 conversion (vectorized, grid-stride) ----------
__global__ __launch_bounds__(256)
void cvt_f32_bf16(const float* __restrict__ in, unsigned short* __restrict__ out, long n4) {
  long i = (long)blockIdx.x * blockDim.x + threadIdx.x;
  long stride = (long)gridDim.x * blockDim.x;
  for (; i < n4; i += stride) {
    f32x4 v = reinterpret_cast<const f32x4*>(in)[i];
    ushort4v p;
#pragma unroll
    for (int e = 0; e < 4; ++e) {
      __bf16 b = (__bf16)v[e];
      p[e] = __builtin_bit_cast(unsigned short, b);
    }
    reinterpret_cast<ushort4v*>(out)[i] = p;
  }
}

// ---------------- XA = X @ lora_A  (fp32, tiled, [8192,16]) -----------------
__global__ __launch_bounds__(256)
void xa_kernel(const float* __restrict__ X, const float* __restrict__ A, float* __restrict__ XAo) {
  constexpr int K = 4096, TM = 32, KC = 64;
  __shared__ float Xs[TM][68];     // pad: row stride 272 B (16B-aligned, breaks pow2)
  __shared__ float Asm[KC][16];
  const int t = threadIdx.x;
  const int m0 = blockIdx.x * TM;
  const int crow = t >> 3;         // 0..31
  const int r0 = (t & 7) * 2;      // 0,2,..,14
  float a0 = 0.f, a1 = 0.f;
  for (int k0 = 0; k0 < K; k0 += KC) {
#pragma unroll
    for (int rep = 0; rep < 2; ++rep) {
      int idx = rep * 256 + t;
      int row = idx >> 4, c4 = (idx & 15) * 4;
      *reinterpret_cast<f32x4*>(&Xs[row][c4]) =
          *reinterpret_cast<const f32x4*>(X + (size_t)(m0 + row) * K + k0 + c4);
    }
    {
      int row = t >> 2, c4 = (t & 3) * 4;
      *reinterpret_cast<f32x4*>(&Asm[row][c4]) =
          *reinterpret_cast<const f32x4*>(A + (size_t)(k0 + row) * 16 + c4);
    }
    __syncthreads();
#pragma unroll
    for (int kk = 0; kk < KC; ++kk) {
      float xv = Xs[crow][kk];
      a0 += xv * Asm[kk][r0];
      a1 += xv * Asm[kk][r0 + 1];
    }
    __syncthreads();
  }
  XAo[(size_t)(m0 + crow) * 16 + r0] = a0;
  XAo[(size_t)(m0 + crow) * 16 + r0 + 1] = a1;
}

// ---------------- main GEMM: out = Xb @ Wb^T + b + XA @ Bl ------------------
// 128x128 tile, 4 waves (2x2), BK=32, mfma_f32_16x16x32_bf16, gload_lds width 16
__global__ __launch_bounds__(256, 2)
void gemm_lora(const __bf16* __restrict__ Xb, const __bf16* __restrict__ Wb,
               const float* __restrict__ bias, const float* __restrict__ XA,
               const float* __restrict__ Bl, float* __restrict__ out) {
  constexpr int N = 4096, K = 4096, BK = 32, NKT = K / BK;
  __shared__ __bf16 As[2][128 * 32];
  __shared__ __bf16 Bs[2][128 * 32];
  __shared__ float XAs[128 * 16];
  __shared__ float Bls[16 * 128];

  const int t = threadIdx.x;
  const int lane = t & 63, w = t >> 6;
  const int wr = w >> 1, wc = w & 1;
  const int m0 = blockIdx.y * 128, n0 = blockIdx.x * 128;
  const int fr = lane & 15, fg = lane >> 4;

  // stage XA tile [128][16] and Bl tile [16][128] (fp32, once)
  {
    int row = t >> 1, rc = (t & 1) * 8;
    *reinterpret_cast<f32x4*>(&XAs[row * 16 + rc]) =
        *reinterpret_cast<const f32x4*>(XA + (size_t)(m0 + row) * 16 + rc);
    *reinterpret_cast<f32x4*>(&XAs[row * 16 + rc + 4]) =
        *reinterpret_cast<const f32x4*>(XA + (size_t)(m0 + row) * 16 + rc + 4);
    int r2 = t >> 4, c2 = (t & 15) * 8;
    *reinterpret_cast<f32x4*>(&Bls[r2 * 128 + c2]) =
        *reinterpret_cast<const f32x4*>(Bl + (size_t)r2 * N + n0 + c2);
    *reinterpret_cast<f32x4*>(&Bls[r2 * 128 + c2 + 4]) =
        *reinterpret_cast<const f32x4*>(Bl + (size_t)r2 * N + n0 + c2 + 4);
  }

  const int srow = w * 32 + (lane >> 2);   // global row this lane sources
  const int scol = (lane & 3) * 8;         // k-offset (bf16 elems) this lane sources
  auto stage = [&](int buf, int kt) {
    const size_t k0 = (size_t)kt * BK;
#pragma unroll
    for (int c = 0; c < 2; ++c) {
      int r = srow + c * 16;
      gload16(Xb + (size_t)(m0 + r) * K + k0 + scol, &As[buf][(w * 32 + c * 16) * 32]);
      gload16(Wb + (size_t)(n0 + r) * K + k0 + scol, &Bs[buf][(w * 32 + c * 16) * 32]);
    }
  };

  f32x4 acc[4][4];
#pragma unroll
  for (int i = 0; i < 4; ++i)
#pragma unroll
    for (int j = 0; j < 4; ++j) acc[i][j] = (f32x4)0.f;

  stage(0, 0);
  __syncthreads();
  int cur = 0;
  for (int kt = 0; kt < NKT; ++kt) {
    if (kt + 1 < NKT) stage(cur ^ 1, kt + 1);  // async prefetch into other buffer
    bf16x8 af[4], bfv[4];
    const int abase = (wr * 64 + fr) * 32 + fg * 8;
    const int bbase = (wc * 64 + fr) * 32 + fg * 8;
#pragma unroll
    for (int i = 0; i < 4; ++i) {
      af[i]  = *reinterpret_cast<const bf16x8*>(&As[cur][abase + i * 16 * 32]);
      bfv[i] = *reinterpret_cast<const bf16x8*>(&Bs[cur][bbase + i * 16 * 32]);
    }
#pragma unroll
    for (int i = 0; i < 4; ++i)
#pragma unroll
      for (int j = 0; j < 4; ++j)
        acc[i][j] = __builtin_amdgcn_mfma_f32_16x16x32_bf16(af[i], bfv[j], acc[i][j], 0, 0, 0);
    __syncthreads();  // drains vmcnt (prefetch landed) + all reads of cur done
    cur ^= 1;
  }

  // epilogue: + bias + XA @ Bl (fp32), store
#pragma unroll
  for (int j = 0; j < 4; ++j) {
    const int cl = wc * 64 + j * 16 + fr;  // local col 0..127
    const int col = n0 + cl;
    const float bb = bias[col];
    float blc[16];
#pragma unroll
    for (int r = 0; r < 16; ++r) blc[r] = Bls[r * 128 + cl];
#pragma unroll
    for (int i = 0; i < 4; ++i) {
#pragma unroll
      for (int q = 0; q < 4; ++q) {
        const int rl = wr * 64 + i * 16 + fg * 4 + q;  // local row 0..127
        float s = acc[i][j][q] + bb;
#pragma unroll
        for (int r = 0; r < 16; ++r) s += XAs[rl * 16 + r] * blc[r];
        out[(size_t)(m0 + rl) * N + col] = s;
      }
    }
  }
}

extern "C" void kernel_launch(void* const* d_in, const int* in_sizes, int n_in,
                              void* d_out, int out_size, void* d_ws, size_t ws_size,
                              hipStream_t stream) {
  const float* x  = (const float*)d_in[0];   // [4,2048,4096] -> [8192,4096]
  const float* W  = (const float*)d_in[1];   // [4096,4096]
  const float* b  = (const float*)d_in[2];   // [4096]
  const float* lA = (const float*)d_in[3];   // [4096,16]
  const float* lB = (const float*)d_in[4];   // [16,4096]
  float* out = (float*)d_out;                // [8192,4096] fp32

  char* ws = (char*)d_ws;
  unsigned short* Xb = (unsigned short*)ws;                          // 67,108,864 B
  unsigned short* Wb = (unsigned short*)(ws + 67108864);             // 33,554,432 B
  float* XA = (float*)(ws + 67108864 + 33554432);                    // 524,288 B

  cvt_f32_bf16<<<2048, 256, 0, stream>>>(x, Xb, (long)8192 * 4096 / 4);
  cvt_f32_bf16<<<1024, 256, 0, stream>>>(W, Wb, (long)4096 * 4096 / 4);
  xa_kernel<<<8192 / 32, 256, 0, stream>>>(x, lA, XA);

  dim3 grid(4096 / 128, 8192 / 128);  // (n-tiles=32, m-tiles=64)
  gemm_lora<<<grid, dim3(256), 0, stream>>>((const __bf16*)Xb, (const __bf16*)Wb, b, XA, lB, out);
}

// Round 2
// 459.955 us; speedup vs baseline: 3.2457x; 3.2457x over previous
//
#include <hip/hip_runtime.h>

typedef float f32x4 __attribute__((ext_vector_type(4)));
typedef __bf16 bf16x8 __attribute__((ext_vector_type(8)));
typedef unsigned short ushort4v __attribute__((ext_vector_type(4)));

#define GLOBAL_AS __attribute__((address_space(1)))
#define LDS_AS    __attribute__((address_space(3)))

static __device__ __forceinline__ void gload16(const void* g, void* l) {
  __builtin_amdgcn_global_load_lds((const GLOBAL_AS void*)g, (LDS_AS void*)l, 16, 0, 0);
}

// ---------------- fp32 -> bf16 conversion (vectorized, grid-stride) ----------
__global__ __launch_bounds__(256)
void cvt_f32_bf16(const float* __restrict__ in, unsigned short* __restrict__ out, long n4) {
  long i = (long)blockIdx.x * blockDim.x + threadIdx.x;
  long stride = (long)gridDim.x * blockDim.x;
  for (; i < n4; i += stride) {
    f32x4 v = reinterpret_cast<const f32x4*>(in)[i];
    ushort4v p;
#pragma unroll
    for (int e = 0; e < 4; ++e) {
      __bf16 b = (__bf16)v[e];
      p[e] = __builtin_bit_cast(unsigned short, b);
    }
    reinterpret_cast<ushort4v*>(out)[i] = p;
  }
}

// ------- XAb = bf16(X @ lora_A), [8192][32] with cols 16..31 zeroed ---------
__global__ __launch_bounds__(256)
void xa_kernel(const float* __restrict__ X, const float* __restrict__ A, __bf16* __restrict__ XAb) {
  constexpr int K = 4096, TM = 32, KC = 64;
  __shared__ float Xs[TM][68];     // pad: row stride 272 B (16B-aligned, breaks pow2)
  __shared__ float Asm[KC][16];
  const int t = threadIdx.x;
  const int m0 = blockIdx.x * TM;
  const int crow = t >> 3;         // 0..31
  const int r0 = (t & 7) * 2;      // 0,2,..,14
  float a0 = 0.f, a1 = 0.f;
  for (int k0 = 0; k0 < K; k0 += KC) {
#pragma unroll
    for (int rep = 0; rep < 2; ++rep) {
      int idx = rep * 256 + t;
      int row = idx >> 4, c4 = (idx & 15) * 4;
      *reinterpret_cast<f32x4*>(&Xs[row][c4]) =
          *reinterpret_cast<const f32x4*>(X + (size_t)(m0 + row) * K + k0 + c4);
    }
    {
      int row = t >> 2, c4 = (t & 3) * 4;
      *reinterpret_cast<f32x4*>(&Asm[row][c4]) =
          *reinterpret_cast<const f32x4*>(A + (size_t)(k0 + row) * 16 + c4);
    }
    __syncthreads();
#pragma unroll
    for (int kk = 0; kk < KC; ++kk) {
      float xv = Xs[crow][kk];
      a0 += xv * Asm[kk][r0];
      a1 += xv * Asm[kk][r0 + 1];
    }
    __syncthreads();
  }
  const size_t base = (size_t)(m0 + crow) * 32;
  XAb[base + r0]      = (__bf16)a0;
  XAb[base + r0 + 1]  = (__bf16)a1;
  XAb[base + 16 + r0]     = (__bf16)0.f;   // zero-pad k=16..31
  XAb[base + 16 + r0 + 1] = (__bf16)0.f;
}

// ------- BlT[col][k] = bf16(Bl[k][col]), [4096][32], k>=16 zero -------------
__global__ __launch_bounds__(256)
void blt_kernel(const float* __restrict__ Bl, __bf16* __restrict__ BlT) {
  int idx = blockIdx.x * 256 + threadIdx.x;   // 4096*32 = 131072 total
  int col = idx >> 5, k = idx & 31;
  float v = (k < 16) ? Bl[(size_t)k * 4096 + col] : 0.f;
  BlT[idx] = (__bf16)v;
}

// ---------------- main GEMM: out = [Xb|XAb] @ [Wb|BlT]^T + b ----------------
// 128x128 tile, 4 waves (2x2), BK=32, mfma_f32_16x16x32_bf16, gload_lds w16,
// LDS slot-swizzle (pre-swizzled global source + swizzled read), XCD swizzle.
__global__ __launch_bounds__(256, 4)
void gemm_lora(const __bf16* __restrict__ Xb, const __bf16* __restrict__ Wb,
               const __bf16* __restrict__ XAb, const __bf16* __restrict__ BlT,
               const float* __restrict__ bias, float* __restrict__ out) {
  constexpr int N = 4096, K = 4096, BK = 32, NKT = K / BK;  // 128 + 1 lora tile
  __shared__ __bf16 As[2][128 * 32];
  __shared__ __bf16 Bs[2][128 * 32];

  const int t = threadIdx.x;
  const int lane = t & 63, w = t >> 6;
  const int wr = w >> 1, wc = w & 1;
  // XCD-aware swizzle: grid=2048 (64 mt x 32 nt). XCD owns an 8-mt slab;
  // walk nt with a 4-mt inner group (4MB A-panel group stays L2-resident).
  const int bid = blockIdx.x;
  const int xcd = bid & 7, lid = bid >> 3;            // lid 0..255
  const int mt = xcd * 8 + (lid >> 7) * 4 + (lid & 3);
  const int nt = (lid >> 2) & 31;
  const int m0 = mt * 128, n0 = nt * 128;
  const int fr = lane & 15, fg = lane >> 4;

  const int lrow0 = w * 32 + (lane >> 2);  // staged local row (c=0)
  const int slot = lane & 3;

  auto stage = [&](int buf, int kt) {
    const bool last = (kt == NKT);
    const __bf16* pa = last ? XAb : (Xb + (size_t)kt * BK);
    const __bf16* pb = last ? BlT : (Wb + (size_t)kt * BK);
    const size_t ld = last ? 32 : (size_t)K;
#pragma unroll
    for (int c = 0; c < 2; ++c) {
      const int lrow = lrow0 + c * 16;
      const int sc = (slot ^ ((lrow >> 1) & 3)) * 8;  // pre-swizzled source col
      gload16(pa + (size_t)(m0 + lrow) * ld + sc, &As[buf][(w * 32 + c * 16) * 32]);
      gload16(pb + (size_t)(n0 + lrow) * ld + sc, &Bs[buf][(w * 32 + c * 16) * 32]);
    }
  };

  f32x4 acc[4][4];
#pragma unroll
  for (int i = 0; i < 4; ++i)
#pragma unroll
    for (int j = 0; j < 4; ++j) acc[i][j] = (f32x4)0.f;

  stage(0, 0);
  __syncthreads();
  int cur = 0;
  for (int kt = 0; kt <= NKT; ++kt) {       // 129 iters: last one is the LoRA tile
    if (kt < NKT) stage(cur ^ 1, kt + 1);   // async prefetch into other buffer
    bf16x8 af[4], bfv[4];
#pragma unroll
    for (int i = 0; i < 4; ++i) {
      const int ar = wr * 64 + i * 16 + fr;
      const int br = wc * 64 + i * 16 + fr;
      af[i]  = *reinterpret_cast<const bf16x8*>(&As[cur][ar * 32 + (fg ^ ((ar >> 1) & 3)) * 8]);
      bfv[i] = *reinterpret_cast<const bf16x8*>(&Bs[cur][br * 32 + (fg ^ ((br >> 1) & 3)) * 8]);
    }
#pragma unroll
    for (int i = 0; i < 4; ++i)
#pragma unroll
      for (int j = 0; j < 4; ++j)
        acc[i][j] = __builtin_amdgcn_mfma_f32_16x16x32_bf16(af[i], bfv[j], acc[i][j], 0, 0, 0);
    __syncthreads();  // drains vmcnt (prefetch landed) + all reads of cur done
    cur ^= 1;
  }

  // epilogue: + bias, store
#pragma unroll
  for (int j = 0; j < 4; ++j) {
    const int col = n0 + wc * 64 + j * 16 + fr;
    const float bb = bias[col];
#pragma unroll
    for (int i = 0; i < 4; ++i) {
#pragma unroll
      for (int q = 0; q < 4; ++q) {
        const int rl = wr * 64 + i * 16 + fg * 4 + q;
        out[(size_t)(m0 + rl) * N + col] = acc[i][j][q] + bb;
      }
    }
  }
}

extern "C" void kernel_launch(void* const* d_in, const int* in_sizes, int n_in,
                              void* d_out, int out_size, void* d_ws, size_t ws_size,
                              hipStream_t stream) {
  const float* x  = (const float*)d_in[0];   // [4,2048,4096] -> [8192,4096]
  const float* W  = (const float*)d_in[1];   // [4096,4096]
  const float* b  = (const float*)d_in[2];   // [4096]
  const float* lA = (const float*)d_in[3];   // [4096,16]
  const float* lB = (const float*)d_in[4];   // [16,4096]
  float* out = (float*)d_out;                // [8192,4096] fp32

  char* ws = (char*)d_ws;
  unsigned short* Xb = (unsigned short*)ws;                     // 67,108,864 B
  unsigned short* Wb = (unsigned short*)(ws + 67108864);        // 33,554,432 B
  __bf16* XAb = (__bf16*)(ws + 67108864 + 33554432);            //    524,288 B
  __bf16* BlT = (__bf16*)(ws + 67108864 + 33554432 + 524288);   //    262,144 B

  cvt_f32_bf16<<<2048, 256, 0, stream>>>(x, Xb, (long)8192 * 4096 / 4);
  cvt_f32_bf16<<<1024, 256, 0, stream>>>(W, Wb, (long)4096 * 4096 / 4);
  xa_kernel<<<8192 / 32, 256, 0, stream>>>(x, lA, XAb);
  blt_kernel<<<131072 / 256, 256, 0, stream>>>(lB, BlT);

  gemm_lora<<<dim3(2048), dim3(256), 0, stream>>>((const __bf16*)Xb, (const __bf16*)Wb,
                                                  XAb, BlT, b, out);
}

// Round 4
// 338.549 us; speedup vs baseline: 4.4096x; 1.3586x over previous
//
#include <hip/hip_runtime.h>

typedef float f32x4 __attribute__((ext_vector_type(4)));
typedef __bf16 bf16x8 __attribute__((ext_vector_type(8)));
typedef __bf16 bf16x4 __attribute__((ext_vector_type(4)));

#define GLOBAL_AS __attribute__((address_space(1)))
#define LDS_AS    __attribute__((address_space(3)))

static __device__ __forceinline__ void gload16(const void* g, void* l) {
  __builtin_amdgcn_global_load_lds((const GLOBAL_AS void*)g, (LDS_AS void*)l, 16, 0, 0);
}

#define BAR() __builtin_amdgcn_s_barrier()
#define WAITL0() do { asm volatile("s_waitcnt lgkmcnt(0)" ::: "memory"); __builtin_amdgcn_sched_barrier(0); } while (0)

// ---------------- fused: Xb = bf16(X); XAb = bf16(X @ lora_A) [8192][64] ----
__global__ __launch_bounds__(256)
void xa_cvt(const float* __restrict__ X, const float* __restrict__ A,
            __bf16* __restrict__ Xb, __bf16* __restrict__ XAb) {
  constexpr int K = 4096, TM = 16, KC = 64;
  __shared__ float Xs[TM][68];
  __shared__ float Asm[KC][16];
  const int t = threadIdx.x;
  const int m0 = blockIdx.x * TM;
  const int crow = t >> 4, rr = t & 15;
  float acc = 0.f;
  for (int k0 = 0; k0 < K; k0 += KC) {
    f32x4 v = *reinterpret_cast<const f32x4*>(X + (size_t)(m0 + crow) * K + k0 + rr * 4);
    *reinterpret_cast<f32x4*>(&Xs[crow][rr * 4]) = v;
    bf16x4 p;
#pragma unroll
    for (int e = 0; e < 4; ++e) p[e] = (__bf16)v[e];
    *reinterpret_cast<bf16x4*>(Xb + (size_t)(m0 + crow) * K + k0 + rr * 4) = p;
    {
      int row = t >> 2, c4 = (t & 3) * 4;
      *reinterpret_cast<f32x4*>(&Asm[row][c4]) =
          *reinterpret_cast<const f32x4*>(A + (size_t)(k0 + row) * 16 + c4);
    }
    __syncthreads();
#pragma unroll 16
    for (int kk = 0; kk < KC; ++kk) acc += Xs[crow][kk] * Asm[kk][rr];
    __syncthreads();
  }
  const size_t base = (size_t)(m0 + crow) * 64;
  XAb[base + rr] = (__bf16)acc;
  XAb[base + 16 + rr] = (__bf16)0.f;
  XAb[base + 32 + rr] = (__bf16)0.f;
  XAb[base + 48 + rr] = (__bf16)0.f;
}

// ---------------- W -> bf16 ----------------
__global__ __launch_bounds__(256)
void cvt_f32_bf16(const float* __restrict__ in, __bf16* __restrict__ out, long n4) {
  long i = (long)blockIdx.x * blockDim.x + threadIdx.x;
  long stride = (long)gridDim.x * blockDim.x;
  for (; i < n4; i += stride) {
    f32x4 v = reinterpret_cast<const f32x4*>(in)[i];
    bf16x4 p;
#pragma unroll
    for (int e = 0; e < 4; ++e) p[e] = (__bf16)v[e];
    reinterpret_cast<bf16x4*>(out)[i] = p;
  }
}

// ------- BlT[col][k] = bf16(Bl[k][col]), [4096][64], k>=16 zero -------------
__global__ __launch_bounds__(256)
void blt64(const float* __restrict__ Bl, __bf16* __restrict__ BlT) {
  int idx = blockIdx.x * 256 + threadIdx.x;   // 4096*64
  int col = idx >> 6, k = idx & 63;
  float v = (k < 16) ? Bl[(size_t)k * 4096 + col] : 0.f;
  BlT[idx] = (__bf16)v;
}

// ---------------- 256x256 8-phase GEMM: out = [Xb|XAb] @ [Wb|BlT]^T + b -----
// 8 waves (2Mx4N), BK=64, zero-conflict XOR swizzle (slot ^= (row>>1)&3),
// counted vmcnt(4), raw s_barrier, setprio, bijective XCD swizzle.
// LDS layout: A[buf][half][rowBlk 0..7][colBlk 0..1] 1024B subtiles (16rx32c),
// then B same, 131072 B total.
__global__ __launch_bounds__(512, 2)
void gemm8(const __bf16* __restrict__ Xb, const __bf16* __restrict__ Wb,
           const __bf16* __restrict__ XAb, const __bf16* __restrict__ BlT,
           const float* __restrict__ bias, float* __restrict__ out) {
  constexpr int N = 4096, K = 4096;
  __shared__ __align__(16) char sm[131072];
  char* Asm_ = sm;
  char* Bsm_ = sm + 65536;

  const int t = threadIdx.x;
  const int lane = t & 63, w = t >> 6;
  const int wr = w >> 2, wc = w & 3;          // wave owns rows wr*128, cols wc*64
  const int fr = lane & 15, fg = lane >> 4;

  // XCD swizzle: grid 512 = 32 mt x 16 nt; bijective; 2-mt (4MB A) inner group.
  const int bid = blockIdx.x;
  const int xcd = bid & 7, l = bid >> 3;                 // l: 0..63
  const int mt = (xcd << 2) | ((l >> 4) & 2) | (l & 1);  // 0..31
  const int nt = (l >> 1) & 15;                          // 0..15
  const int m0 = mt * 256, n0 = nt * 256;

  // staging lane constants: lane writes linear LDS (row=lane>>2, slot=lane&3);
  // source column slot is inverse-swizzled: slot ^ ((row>>1)&3)
  const int sRow = w * 16 + (lane >> 2);                          // row in half
  const int sColB = (((lane & 3) ^ ((lane >> 3) & 3)) << 4);      // byte offset
  // frag read: row fr, logical slot fg -> physical slot fg ^ ((fr>>1)&3)
  const int rdOff = fr * 64 + ((fg ^ ((fr >> 1) & 3)) << 4);
  const int rdOffA = wr * 16384 + rdOff;
  const int rdOffB = (wc >> 1) * 16384 + (wc & 1) * 8192 + rdOff;

  auto stageA = [&](int h, int tt) {
    char* dst = Asm_ + (tt & 1) * 32768 + h * 16384 + w * 2048;
    const char* g;
    if (tt < 64) g = (const char*)(Xb + (size_t)(m0 + h * 128 + sRow) * K + (size_t)tt * 64) + sColB;
    else         g = (const char*)(XAb + (size_t)(m0 + h * 128 + sRow) * 64) + sColB;
    gload16(g, dst);
    gload16(g + 64, dst + 1024);   // colBlk 1 (+32 cols)
  };
  auto stageB = [&](int h, int tt) {
    char* dst = Bsm_ + (tt & 1) * 32768 + h * 16384 + w * 2048;
    const char* g;
    if (tt < 64) g = (const char*)(Wb + (size_t)(n0 + h * 128 + sRow) * K + (size_t)tt * 64) + sColB;
    else         g = (const char*)(BlT + (size_t)(n0 + h * 128 + sRow) * 64) + sColB;
    gload16(g, dst);
    gload16(g + 64, dst + 1024);
  };

  auto rdA = [&](int b, int mf, int kk) -> bf16x8 {
    return *reinterpret_cast<const bf16x8*>(Asm_ + b * 32768 + (mf * 2 + kk) * 1024 + rdOffA);
  };
  auto rdB = [&](int b, int nf, int kk) -> bf16x8 {
    return *reinterpret_cast<const bf16x8*>(Bsm_ + b * 32768 + (nf * 2 + kk) * 1024 + rdOffB);
  };

  f32x4 acc[8][4];
#pragma unroll
  for (int i = 0; i < 8; ++i)
#pragma unroll
    for (int j = 0; j < 4; ++j) acc[i][j] = (f32x4)0.f;

  bf16x8 aF[4][2], bL[2][2], bH[2][2];

  auto MF = [&](bf16x8 (&af)[4][2], bf16x8 (&bf_)[2][2], int mi, int ni) {
#pragma unroll
    for (int i = 0; i < 4; ++i)
#pragma unroll
      for (int j = 0; j < 2; ++j)
#pragma unroll
        for (int kk = 0; kk < 2; ++kk)
          acc[mi * 4 + i][ni * 2 + j] = __builtin_amdgcn_mfma_f32_16x16x32_bf16(
              af[i][kk], bf_[j][kk], acc[mi * 4 + i][ni * 2 + j], 0, 0, 0);
  };

  auto tile_step = [&](int tv) {
    const int b = tv & 1;
    // P1: 12 ds_reads (A mf0..3, B nf0..1), stage A0(t+1)
#pragma unroll
    for (int i = 0; i < 4; ++i)
#pragma unroll
      for (int kk = 0; kk < 2; ++kk) aF[i][kk] = rdA(b, i, kk);
#pragma unroll
    for (int j = 0; j < 2; ++j)
#pragma unroll
      for (int kk = 0; kk < 2; ++kk) bL[j][kk] = rdB(b, j, kk);
    stageA(0, tv + 1);
    BAR(); WAITL0();
    __builtin_amdgcn_s_setprio(1); MF(aF, bL, 0, 0); __builtin_amdgcn_s_setprio(0);
    BAR();
    // P2: 4 reads (B nf2..3), stage A1(t+1)
#pragma unroll
    for (int j = 0; j < 2; ++j)
#pragma unroll
      for (int kk = 0; kk < 2; ++kk) bH[j][kk] = rdB(b, 2 + j, kk);
    stageA(1, tv + 1);
    BAR(); WAITL0();
    __builtin_amdgcn_s_setprio(1); MF(aF, bH, 0, 1); __builtin_amdgcn_s_setprio(0);
    BAR();
    // P3: 8 reads (A mf4..7), stage B0(t+2)
#pragma unroll
    for (int i = 0; i < 4; ++i)
#pragma unroll
      for (int kk = 0; kk < 2; ++kk) aF[i][kk] = rdA(b, 4 + i, kk);
    if (tv + 2 <= 64) stageB(0, tv + 2);
    BAR(); WAITL0();
    __builtin_amdgcn_s_setprio(1); MF(aF, bH, 1, 1); __builtin_amdgcn_s_setprio(0);
    BAR();
    // P4: 0 reads, stage B1(t+2), counted vmcnt checkpoint (leaves B(t+2) in flight)
    if (tv + 2 <= 64) stageB(1, tv + 2);
    BAR(); WAITL0();
    __builtin_amdgcn_s_setprio(1); MF(aF, bL, 1, 0); __builtin_amdgcn_s_setprio(0);
    asm volatile("s_waitcnt vmcnt(4)" ::: "memory");
    BAR();
  };

  // prologue: A(0),B(0),B(1) issued; vmcnt(4) retires A(0),B(0); B(1) in flight
  stageA(0, 0); stageA(1, 0); stageB(0, 0); stageB(1, 0); stageB(0, 1); stageB(1, 1);
  asm volatile("s_waitcnt vmcnt(4)" ::: "memory");
  BAR();

  for (int tp = 0; tp < 32; ++tp) { tile_step(2 * tp); tile_step(2 * tp + 1); }

  // LoRA tile 64 (buf 0): drain everything, then pure-register MFMA
  asm volatile("s_waitcnt vmcnt(0)" ::: "memory");
  BAR();
  {
#pragma unroll
    for (int i = 0; i < 4; ++i)
#pragma unroll
      for (int kk = 0; kk < 2; ++kk) aF[i][kk] = rdA(0, i, kk);
#pragma unroll
    for (int j = 0; j < 2; ++j)
#pragma unroll
      for (int kk = 0; kk < 2; ++kk) { bL[j][kk] = rdB(0, j, kk); bH[j][kk] = rdB(0, 2 + j, kk); }
    MF(aF, bL, 0, 0); MF(aF, bH, 0, 1);
#pragma unroll
    for (int i = 0; i < 4; ++i)
#pragma unroll
      for (int kk = 0; kk < 2; ++kk) aF[i][kk] = rdA(0, 4 + i, kk);
    MF(aF, bH, 1, 1); MF(aF, bL, 1, 0);
  }

  // epilogue: + bias, store fp32
  float bb[4];
#pragma unroll
  for (int j = 0; j < 4; ++j) bb[j] = bias[n0 + wc * 64 + j * 16 + fr];
#pragma unroll
  for (int i = 0; i < 8; ++i) {
    const int row0 = m0 + wr * 128 + i * 16 + fg * 4;
#pragma unroll
    for (int j = 0; j < 4; ++j) {
      const int col = n0 + wc * 64 + j * 16 + fr;
#pragma unroll
      for (int q = 0; q < 4; ++q)
        out[(size_t)(row0 + q) * N + col] = acc[i][j][q] + bb[j];
    }
  }
}

extern "C" void kernel_launch(void* const* d_in, const int* in_sizes, int n_in,
                              void* d_out, int out_size, void* d_ws, size_t ws_size,
                              hipStream_t stream) {
  const float* x  = (const float*)d_in[0];   // [4,2048,4096] -> [8192,4096]
  const float* W  = (const float*)d_in[1];   // [4096,4096]
  const float* b  = (const float*)d_in[2];   // [4096]
  const float* lA = (const float*)d_in[3];   // [4096,16]
  const float* lB = (const float*)d_in[4];   // [16,4096]
  float* out = (float*)d_out;                // [8192,4096] fp32

  char* ws = (char*)d_ws;
  __bf16* Xb  = (__bf16*)ws;                                   // 67,108,864 B
  __bf16* Wb  = (__bf16*)(ws + 67108864);                      // 33,554,432 B
  __bf16* XAb = (__bf16*)(ws + 100663296);                     //  1,048,576 B
  __bf16* BlT = (__bf16*)(ws + 101711872);                     //    524,288 B

  xa_cvt<<<8192 / 16, 256, 0, stream>>>(x, lA, Xb, XAb);
  cvt_f32_bf16<<<1024, 256, 0, stream>>>(W, Wb, (long)4096 * 4096 / 4);
  blt64<<<4096 * 64 / 256, 256, 0, stream>>>(lB, BlT);

  gemm8<<<dim3(512), dim3(512), 0, stream>>>(Xb, Wb, XAb, BlT, b, out);
}

// Round 5
// 336.443 us; speedup vs baseline: 4.4372x; 1.0063x over previous
//
#include <hip/hip_runtime.h>

typedef float f32x4 __attribute__((ext_vector_type(4)));
typedef __bf16 bf16x8 __attribute__((ext_vector_type(8)));
typedef __bf16 bf16x4 __attribute__((ext_vector_type(4)));

#define GLOBAL_AS __attribute__((address_space(1)))
#define LDS_AS    __attribute__((address_space(3)))

static __device__ __forceinline__ void gload16(const void* g, void* l) {
  __builtin_amdgcn_global_load_lds((const GLOBAL_AS void*)g, (LDS_AS void*)l, 16, 0, 0);
}

#define BAR() __builtin_amdgcn_s_barrier()
#define WAITL0() do { asm volatile("s_waitcnt lgkmcnt(0)" ::: "memory"); __builtin_amdgcn_sched_barrier(0); } while (0)

// ---- fused: Xb = bf16(X); XAb = bf16(X @ lora_A) [8192][64], cols>=16 zero --
__global__ __launch_bounds__(256)
void xa_cvt(const float* __restrict__ X, const float* __restrict__ A,
            __bf16* __restrict__ Xb, __bf16* __restrict__ XAb) {
  constexpr int K = 4096, TM = 16, KC = 64;
  __shared__ float Xs[TM][68];   // stride 68 ≡ 4 mod 32 banks -> ≤2-way on reads
  __shared__ float At[16][68];   // A-chunk transposed: At[r][kk]
  const int t = threadIdx.x;
  const int m0 = blockIdx.x * TM;
  const int lrow = t >> 4, c4 = (t & 15) * 4;   // X load/convert mapping
  const int orow = t >> 4, oc = t & 15;          // dot output mapping
  const int akk = t >> 2, ar4 = (t & 3) * 4;     // A transpose-load mapping
  f32x4 av = (f32x4)0.f;
  for (int k0 = 0; k0 < K; k0 += KC) {
    const float* gx = X + (size_t)(m0 + lrow) * K + k0 + c4;
    f32x4 u = *reinterpret_cast<const f32x4*>(gx);
    *reinterpret_cast<f32x4*>(&Xs[lrow][c4]) = u;
    bf16x4 p;
#pragma unroll
    for (int e = 0; e < 4; ++e) p[e] = (__bf16)u[e];
    *reinterpret_cast<bf16x4*>(Xb + (size_t)(m0 + lrow) * K + k0 + c4) = p;
    f32x4 a = *reinterpret_cast<const f32x4*>(A + (size_t)(k0 + akk) * 16 + ar4);
    At[ar4 + 0][akk] = a[0]; At[ar4 + 1][akk] = a[1];
    At[ar4 + 2][akk] = a[2]; At[ar4 + 3][akk] = a[3];
    __syncthreads();
#pragma unroll
    for (int q = 0; q < 16; ++q) {
      f32x4 xv = *reinterpret_cast<const f32x4*>(&Xs[orow][q * 4]);
      av += xv * *reinterpret_cast<const f32x4*>(&At[oc][q * 4]);
    }
    __syncthreads();
  }
  const float acc = av[0] + av[1] + av[2] + av[3];
  const size_t base = (size_t)(m0 + orow) * 64;
  XAb[base + oc] = (__bf16)acc;
#pragma unroll
  for (int z = 0; z < 3; ++z) XAb[base + 16 + z * 16 + oc] = (__bf16)0.f;
}

// ---------------- W -> bf16 (16B stores) ----------------
__global__ __launch_bounds__(256)
void cvt_f32_bf16(const float* __restrict__ in, __bf16* __restrict__ out, long n8) {
  long i = (long)blockIdx.x * blockDim.x + threadIdx.x;
  long stride = (long)gridDim.x * blockDim.x;
  for (; i < n8; i += stride) {
    f32x4 u = reinterpret_cast<const f32x4*>(in)[2 * i];
    f32x4 v = reinterpret_cast<const f32x4*>(in)[2 * i + 1];
    bf16x8 p;
#pragma unroll
    for (int e = 0; e < 4; ++e) { p[e] = (__bf16)u[e]; p[4 + e] = (__bf16)v[e]; }
    reinterpret_cast<bf16x8*>(out)[i] = p;
  }
}

// ------- BlT[col][k] = bf16(Bl[k][col]), [4096][64], k>=16 zero -------------
__global__ __launch_bounds__(256)
void blt64(const float* __restrict__ Bl, __bf16* __restrict__ BlT) {
  int idx = blockIdx.x * 256 + threadIdx.x;   // 4096*64
  int col = idx >> 6, k = idx & 63;
  float v = (k < 16) ? Bl[(size_t)k * 4096 + col] : 0.f;
  BlT[idx] = (__bf16)v;
}

// ---------------- 256x256 8-phase GEMM: out = [Xb|XAb] @ [Wb|BlT]^T + b -----
// 8 waves (2Mx4N), BK=64, zero-conflict XOR swizzle, deep ledger:
// tile t stages A1(t+1)@P1, B0(t+2)@P3, B1(t+2)+A0(t+2)@P4, vmcnt(6)/tile.
__global__ __launch_bounds__(512, 2)
void gemm8(const __bf16* __restrict__ Xb, const __bf16* __restrict__ Wb,
           const __bf16* __restrict__ XAb, const __bf16* __restrict__ BlT,
           const float* __restrict__ bias, float* __restrict__ out) {
  constexpr int N = 4096, K = 4096;
  __shared__ __align__(16) char sm[131072];
  char* Asm_ = sm;
  char* Bsm_ = sm + 65536;

  const int t = threadIdx.x;
  const int lane = t & 63, w = t >> 6;
  const int wr = w >> 2, wc = w & 3;
  const int fr = lane & 15, fg = lane >> 4;

  // bijective XCD swizzle: grid 512 = 32 mt x 16 nt; 2-mt inner group.
  const int bid = blockIdx.x;
  const int xcd = bid & 7, l = bid >> 3;
  const int mt = (xcd << 2) | ((l >> 4) & 2) | (l & 1);
  const int nt = (l >> 1) & 15;
  const int m0 = mt * 256, n0 = nt * 256;

  const int sRow = w * 16 + (lane >> 2);
  const int sColB = (((lane & 3) ^ ((lane >> 3) & 3)) << 4);   // inverse swizzle
  const int rdOff = fr * 64 + ((fg ^ ((fr >> 1) & 3)) << 4);
  const int rdOffA = wr * 16384 + rdOff;
  const int rdOffB = (wc >> 1) * 16384 + (wc & 1) * 8192 + rdOff;

  auto stageA = [&](int h, int tt) {
    char* dst = Asm_ + (tt & 1) * 32768 + h * 16384 + w * 2048;
    const char* g;
    if (tt < 64) g = (const char*)(Xb + (size_t)(m0 + h * 128 + sRow) * K + (size_t)tt * 64) + sColB;
    else         g = (const char*)(XAb + (size_t)(m0 + h * 128 + sRow) * 64) + sColB;
    gload16(g, dst);
    gload16(g + 64, dst + 1024);
  };
  auto stageB = [&](int h, int tt) {
    char* dst = Bsm_ + (tt & 1) * 32768 + h * 16384 + w * 2048;
    const char* g;
    if (tt < 64) g = (const char*)(Wb + (size_t)(n0 + h * 128 + sRow) * K + (size_t)tt * 64) + sColB;
    else         g = (const char*)(BlT + (size_t)(n0 + h * 128 + sRow) * 64) + sColB;
    gload16(g, dst);
    gload16(g + 64, dst + 1024);
  };

  auto rdA = [&](int b, int mf, int kk) -> bf16x8 {
    return *reinterpret_cast<const bf16x8*>(Asm_ + b * 32768 + (mf * 2 + kk) * 1024 + rdOffA);
  };
  auto rdB = [&](int b, int nf, int kk) -> bf16x8 {
    return *reinterpret_cast<const bf16x8*>(Bsm_ + b * 32768 + (nf * 2 + kk) * 1024 + rdOffB);
  };

  f32x4 acc[8][4];
#pragma unroll
  for (int i = 0; i < 8; ++i)
#pragma unroll
    for (int j = 0; j < 4; ++j) acc[i][j] = (f32x4)0.f;

  bf16x8 aF[4][2], bL[2][2], bH[2][2];

  auto MF = [&](bf16x8 (&af)[4][2], bf16x8 (&bf_)[2][2], int mi, int ni) {
#pragma unroll
    for (int i = 0; i < 4; ++i)
#pragma unroll
      for (int j = 0; j < 2; ++j)
#pragma unroll
        for (int kk = 0; kk < 2; ++kk)
          acc[mi * 4 + i][ni * 2 + j] = __builtin_amdgcn_mfma_f32_16x16x32_bf16(
              af[i][kk], bf_[j][kk], acc[mi * 4 + i][ni * 2 + j], 0, 0, 0);
  };

  // steady tile: stages A1(t+1)@P1, B0(t+2)@P3, {B1,A0}(t+2)@P4, vmcnt(6)
  auto tile_step = [&](int tv) {
    const int b = tv & 1;
    // P1: 12 ds_reads (A mf0..3, B nf0..1)
#pragma unroll
    for (int i = 0; i < 4; ++i)
#pragma unroll
      for (int kk = 0; kk < 2; ++kk) aF[i][kk] = rdA(b, i, kk);
#pragma unroll
    for (int j = 0; j < 2; ++j)
#pragma unroll
      for (int kk = 0; kk < 2; ++kk) bL[j][kk] = rdB(b, j, kk);
    stageA(1, tv + 1);
    BAR(); WAITL0();
    __builtin_amdgcn_s_setprio(1); MF(aF, bL, 0, 0); __builtin_amdgcn_s_setprio(0);
    BAR();
    // P2: 4 reads (B nf2..3)
#pragma unroll
    for (int j = 0; j < 2; ++j)
#pragma unroll
      for (int kk = 0; kk < 2; ++kk) bH[j][kk] = rdB(b, 2 + j, kk);
    BAR(); WAITL0();
    __builtin_amdgcn_s_setprio(1); MF(aF, bH, 0, 1); __builtin_amdgcn_s_setprio(0);
    BAR();
    // P3: 8 reads (A mf4..7)
#pragma unroll
    for (int i = 0; i < 4; ++i)
#pragma unroll
      for (int kk = 0; kk < 2; ++kk) aF[i][kk] = rdA(b, 4 + i, kk);
    stageB(0, tv + 2);
    BAR(); WAITL0();
    __builtin_amdgcn_s_setprio(1); MF(aF, bH, 1, 1); __builtin_amdgcn_s_setprio(0);
    BAR();
    // P4: 0 reads; stage B1(t+2), A0(t+2); counted vmcnt
    stageB(1, tv + 2);
    stageA(0, tv + 2);
    BAR(); WAITL0();
    __builtin_amdgcn_s_setprio(1); MF(aF, bL, 1, 0); __builtin_amdgcn_s_setprio(0);
    asm volatile("s_waitcnt vmcnt(6)" ::: "memory");
    BAR();
  };

  // prologue: A(0),B(0) + B(1),A0(1); vmcnt(6) retires A(0),B(0)
  stageA(0, 0); stageA(1, 0); stageB(0, 0); stageB(1, 0);
  stageB(0, 1); stageB(1, 1); stageA(0, 1);
  asm volatile("s_waitcnt vmcnt(6)" ::: "memory");
  BAR();

  for (int tv = 0; tv < 63; ++tv) tile_step(tv);

  // peeled tile 63 (b=1): only stage A1(64); full drain at end
  {
    const int b = 1;
#pragma unroll
    for (int i = 0; i < 4; ++i)
#pragma unroll
      for (int kk = 0; kk < 2; ++kk) aF[i][kk] = rdA(b, i, kk);
#pragma unroll
    for (int j = 0; j < 2; ++j)
#pragma unroll
      for (int kk = 0; kk < 2; ++kk) bL[j][kk] = rdB(b, j, kk);
    stageA(1, 64);
    BAR(); WAITL0();
    __builtin_amdgcn_s_setprio(1); MF(aF, bL, 0, 0); __builtin_amdgcn_s_setprio(0);
    BAR();
#pragma unroll
    for (int j = 0; j < 2; ++j)
#pragma unroll
      for (int kk = 0; kk < 2; ++kk) bH[j][kk] = rdB(b, 2 + j, kk);
    BAR(); WAITL0();
    __builtin_amdgcn_s_setprio(1); MF(aF, bH, 0, 1); __builtin_amdgcn_s_setprio(0);
    BAR();
#pragma unroll
    for (int i = 0; i < 4; ++i)
#pragma unroll
      for (int kk = 0; kk < 2; ++kk) aF[i][kk] = rdA(b, 4 + i, kk);
    BAR(); WAITL0();
    __builtin_amdgcn_s_setprio(1); MF(aF, bH, 1, 1); __builtin_amdgcn_s_setprio(0);
    BAR();
    __builtin_amdgcn_s_setprio(1); MF(aF, bL, 1, 0); __builtin_amdgcn_s_setprio(0);
    asm volatile("s_waitcnt vmcnt(0)" ::: "memory");
    BAR();
  }

  // LoRA tile 64 (buf 0): pure LDS reads + MFMA
  {
#pragma unroll
    for (int i = 0; i < 4; ++i)
#pragma unroll
      for (int kk = 0; kk < 2; ++kk) aF[i][kk] = rdA(0, i, kk);
#pragma unroll
    for (int j = 0; j < 2; ++j)
#pragma unroll
      for (int kk = 0; kk < 2; ++kk) { bL[j][kk] = rdB(0, j, kk); bH[j][kk] = rdB(0, 2 + j, kk); }
    MF(aF, bL, 0, 0); MF(aF, bH, 0, 1);
#pragma unroll
    for (int i = 0; i < 4; ++i)
#pragma unroll
      for (int kk = 0; kk < 2; ++kk) aF[i][kk] = rdA(0, 4 + i, kk);
    MF(aF, bH, 1, 1); MF(aF, bL, 1, 0);
  }

  // epilogue: + bias, store fp32
  float bb[4];
#pragma unroll
  for (int j = 0; j < 4; ++j) bb[j] = bias[n0 + wc * 64 + j * 16 + fr];
#pragma unroll
  for (int i = 0; i < 8; ++i) {
    const int row0 = m0 + wr * 128 + i * 16 + fg * 4;
#pragma unroll
    for (int j = 0; j < 4; ++j) {
      const int col = n0 + wc * 64 + j * 16 + fr;
#pragma unroll
      for (int q = 0; q < 4; ++q)
        out[(size_t)(row0 + q) * N + col] = acc[i][j][q] + bb[j];
    }
  }
}

extern "C" void kernel_launch(void* const* d_in, const int* in_sizes, int n_in,
                              void* d_out, int out_size, void* d_ws, size_t ws_size,
                              hipStream_t stream) {
  const float* x  = (const float*)d_in[0];   // [4,2048,4096] -> [8192,4096]
  const float* W  = (const float*)d_in[1];   // [4096,4096]
  const float* b  = (const float*)d_in[2];   // [4096]
  const float* lA = (const float*)d_in[3];   // [4096,16]
  const float* lB = (const float*)d_in[4];   // [16,4096]
  float* out = (float*)d_out;                // [8192,4096] fp32

  char* ws = (char*)d_ws;
  __bf16* Xb  = (__bf16*)ws;                                   // 67,108,864 B
  __bf16* Wb  = (__bf16*)(ws + 67108864);                      // 33,554,432 B
  __bf16* XAb = (__bf16*)(ws + 100663296);                     //  1,048,576 B
  __bf16* BlT = (__bf16*)(ws + 101711872);                     //    524,288 B

  xa_cvt<<<8192 / 16, 256, 0, stream>>>(x, lA, Xb, XAb);
  cvt_f32_bf16<<<1024, 256, 0, stream>>>(W, Wb, (long)4096 * 4096 / 8);
  blt64<<<4096 * 64 / 256, 256, 0, stream>>>(lB, BlT);

  gemm8<<<dim3(512), dim3(512), 0, stream>>>(Xb, Wb, XAb, BlT, b, out);
}